// Round 1
// baseline (1178.809 us; speedup 1.0000x reference)
//
#include <hip/hip_runtime.h>

// Problem constants (also derived at runtime from in_sizes)
// N=50000, E=800000, CUR=128, HID=96, OUT=128

// ---------------------------------------------------------------------------
// K0: detect whether edge_index is int64 (high words of first 1024 row-0
// entries all zero) or int32. Deterministic, input-dependent only.
__global__ void k_flag(const unsigned* __restrict__ ei, int* __restrict__ flag) {
    __shared__ int bad;
    if (threadIdx.x == 0) bad = 0;
    __syncthreads();
    unsigned w = ei[2 * threadIdx.x + 1];  // odd words 1..2047
    if (w != 0) atomicAdd(&bad, 1);
    __syncthreads();
    if (threadIdx.x == 0) *flag = (bad == 0) ? 1 : 0;  // 1 => int64
}

__device__ __forceinline__ int edge_src(const int* ei, int e, int E, int flag) {
    return flag ? ei[2 * e] : ei[e];
}
__device__ __forceinline__ int edge_dst(const int* ei, int e, int E, int flag) {
    return flag ? ei[2 * (E + e)] : ei[E + e];
}

// ---------------------------------------------------------------------------
// K1: xh = x @ pre_W + pre_b   [N,128] @ [128,96] -> [N,96]
__global__ __launch_bounds__(192) void k_xh(const float* __restrict__ x,
                                            const float* __restrict__ W,
                                            const float* __restrict__ b,
                                            float* __restrict__ xh, int N) {
    int half = threadIdx.x >= 96;
    int h = threadIdx.x - 96 * half;
    long n = (long)blockIdx.x * 2 + half;
    if (n >= N) return;
    const float4* xr = (const float4*)(x + n * 128);
    float acc = b[h];
#pragma unroll
    for (int kk = 0; kk < 32; kk++) {
        float4 v = xr[kk];
        int k = kk * 4;
        acc += v.x * W[(k + 0) * 96 + h];
        acc += v.y * W[(k + 1) * 96 + h];
        acc += v.z * W[(k + 2) * 96 + h];
        acc += v.w * W[(k + 3) * 96 + h];
    }
    xh[n * 96 + h] = acc;
}

// ---------------------------------------------------------------------------
// K2: per-edge degree / count accumulation
__global__ void k_deg(const int* __restrict__ ei, const float* __restrict__ ew,
                      float* __restrict__ deg, float* __restrict__ cnt, int E,
                      const int* __restrict__ flagp) {
    int e = blockIdx.x * blockDim.x + threadIdx.x;
    if (e >= E) return;
    int flag = *flagp;
    int d = edge_dst(ei, e, E, flag);
    atomicAdd(&deg[d], ew[e]);
    atomicAdd(&cnt[d], 1.0f);
}

// K3: node-level dinv (ARMA norm) and 1/max(cnt,1) (SAGE mean)
__global__ void k_dinv(const float* __restrict__ deg, const float* __restrict__ cnt,
                       float* __restrict__ dinv, float* __restrict__ minv, int N) {
    int n = blockIdx.x * blockDim.x + threadIdx.x;
    if (n >= N) return;
    float dg = deg[n];
    dinv[n] = dg > 0.f ? rsqrtf(fmaxf(dg, 1e-30f)) : 0.f;
    minv[n] = 1.f / fmaxf(cnt[n], 1.f);
}

// ---------------------------------------------------------------------------
// K4: edge scatter. 32 lanes per edge, 3 feats per lane (96 = 32*3).
// aggrS[dst] += ew * xh[src];  aggrA[dst] += (dinv[src]*ew) * xh[src]
__global__ __launch_bounds__(256) void k_edge(const int* __restrict__ ei,
                                              const float* __restrict__ ew,
                                              const float* __restrict__ xh,
                                              const float* __restrict__ dinv,
                                              float* __restrict__ aggrS,
                                              float* __restrict__ aggrA, int E,
                                              const int* __restrict__ flagp) {
    int lane = threadIdx.x & 31;
    int e = (blockIdx.x * blockDim.x + threadIdx.x) >> 5;
    if (e >= E) return;
    int flag = *flagp;
    int s = edge_src(ei, e, E, flag);
    int d = edge_dst(ei, e, E, flag);
    float w = ew[e];
    float wa = dinv[s] * w;
    const float* row = xh + (long)s * 96;
    float* oS = aggrS + (long)d * 96;
    float* oA = aggrA + (long)d * 96;
#pragma unroll
    for (int i = 0; i < 3; i++) {
        float v = row[lane + 32 * i];
        atomicAdd(oS + lane + 32 * i, v * w);
        atomicAdd(oA + lane + 32 * i, v * wa);
    }
}

// ---------------------------------------------------------------------------
// K5: node epilogue. 4 dots of length 96 per (node, j) thread; 2 nodes/block.
__global__ __launch_bounds__(256) void k_out(
    const float* __restrict__ xh, const float* __restrict__ aggrS,
    const float* __restrict__ aggrA, const float* __restrict__ dinv,
    const float* __restrict__ minv, const float* __restrict__ Wl,
    const float* __restrict__ bl, const float* __restrict__ Wr,
    const float* __restrict__ Wa, const float* __restrict__ Va,
    const float* __restrict__ ba, float* __restrict__ out, int N) {
    int half = threadIdx.x >> 7;
    int j = threadIdx.x & 127;
    long n = (long)blockIdx.x * 2 + half;
    if (n >= N) return;
    const float4* rS = (const float4*)(aggrS + n * 96);
    const float4* rA = (const float4*)(aggrA + n * 96);
    const float4* rX = (const float4*)(xh + n * 96);
    float dS = 0.f, dR = 0.f, dA = 0.f, dV = 0.f;
#pragma unroll
    for (int kk = 0; kk < 24; kk++) {
        float4 vS = rS[kk];
        float4 vA = rA[kk];
        float4 vX = rX[kk];
        int k = kk * 4;
        dS += vS.x * Wl[(k + 0) * 128 + j] + vS.y * Wl[(k + 1) * 128 + j] +
              vS.z * Wl[(k + 2) * 128 + j] + vS.w * Wl[(k + 3) * 128 + j];
        dA += vA.x * Wa[(k + 0) * 128 + j] + vA.y * Wa[(k + 1) * 128 + j] +
              vA.z * Wa[(k + 2) * 128 + j] + vA.w * Wa[(k + 3) * 128 + j];
        dR += vX.x * Wr[(k + 0) * 128 + j] + vX.y * Wr[(k + 1) * 128 + j] +
              vX.z * Wr[(k + 2) * 128 + j] + vX.w * Wr[(k + 3) * 128 + j];
        dV += vX.x * Va[(k + 0) * 128 + j] + vX.y * Va[(k + 1) * 128 + j] +
              vX.z * Va[(k + 2) * 128 + j] + vX.w * Va[(k + 3) * 128 + j];
    }
    float os = minv[n] * dS + bl[j] + dR;                  // SAGE out
    float oa = fmaxf(dinv[n] * dA + dV + ba[j], 0.f);      // ARMA out (ReLU)
    float o1 = os > 0.f ? os : 0.01f * os;                 // leaky
    float o2 = oa > 0.f ? oa : 0.01f * oa;                 // leaky
    out[n * 128 + j] = fmaxf(o1 + o2, 0.f);
}

// ---------------------------------------------------------------------------
extern "C" void kernel_launch(void* const* d_in, const int* in_sizes, int n_in,
                              void* d_out, int out_size, void* d_ws, size_t ws_size,
                              hipStream_t stream) {
    const float* x    = (const float*)d_in[1];
    const int*   ei   = (const int*)d_in[2];
    const float* ew   = (const float*)d_in[3];
    const float* preW = (const float*)d_in[4];
    const float* preb = (const float*)d_in[5];
    const float* Wl   = (const float*)d_in[6];
    const float* bl   = (const float*)d_in[7];
    const float* Wr   = (const float*)d_in[8];
    const float* Wa   = (const float*)d_in[9];
    const float* Va   = (const float*)d_in[10];
    const float* ba   = (const float*)d_in[11];

    const int N = in_sizes[1] / 128;
    const int E = in_sizes[3];

    // ws layout (floats): aggrS[N*96] aggrA[N*96] deg[N] cnt[N] | xh[N*96] dinv[N] minv[N] flag
    float* ws    = (float*)d_ws;
    float* aggrS = ws;
    float* aggrA = aggrS + (size_t)N * 96;
    float* deg   = aggrA + (size_t)N * 96;
    float* cnt   = deg + N;
    float* xh    = cnt + N;
    float* dinv  = xh + (size_t)N * 96;
    float* minv  = dinv + N;
    int*   flag  = (int*)(minv + N);

    // zero the accumulated region (aggrS, aggrA, deg, cnt are contiguous)
    hipMemsetAsync(aggrS, 0, ((size_t)N * 192 + 2 * (size_t)N) * sizeof(float), stream);

    k_flag<<<1, 1024, 0, stream>>>((const unsigned*)ei, flag);
    k_xh<<<(N + 1) / 2, 192, 0, stream>>>(x, preW, preb, xh, N);
    k_deg<<<(E + 255) / 256, 256, 0, stream>>>(ei, ew, deg, cnt, E, flag);
    k_dinv<<<(N + 255) / 256, 256, 0, stream>>>(deg, cnt, dinv, minv, N);
    k_edge<<<(int)(((long)E * 32 + 255) / 256), 256, 0, stream>>>(ei, ew, xh, dinv,
                                                                  aggrS, aggrA, E, flag);
    // output 0: his = x (straight copy)
    hipMemcpyAsync(d_out, (void*)x, (size_t)N * 128 * sizeof(float),
                   hipMemcpyDeviceToDevice, stream);
    // output 1: o3
    k_out<<<(N + 1) / 2, 256, 0, stream>>>(xh, aggrS, aggrA, dinv, minv, Wl, bl, Wr,
                                           Wa, Va, ba, (float*)d_out + (size_t)N * 128, N);
}